// Round 2
// baseline (586.009 us; speedup 1.0000x reference)
//
#include <hip/hip_runtime.h>
#include <hip/hip_bf16.h>

typedef unsigned short u16;
typedef unsigned int   u32;
typedef _Float16 half2v __attribute__((ext_vector_type(2)));

#define HDIM 128
#define IDIM 4
#define TLEN 512
#define GDIM 512   // 4*H

__device__ __forceinline__ float sigm(float x){
  return 1.0f / (1.0f + __expf(-x));
}
__device__ __forceinline__ float tanh_fast(float x){
  float t = fabsf(x);
  float e = __expf(-2.0f * t);          // e in (0,1], no overflow
  float r = (1.0f - e) / (1.0f + e);
  return copysignf(r, x);
}

#if __has_builtin(__builtin_amdgcn_fdot2)
__device__ __forceinline__ float fdot2(half2v a, half2v b, float c){
  return __builtin_amdgcn_fdot2(a, b, c, false);
}
#else
__device__ __forceinline__ float fdot2(half2v a, half2v b, float c){
  return c + (float)a[0]*(float)b[0] + (float)a[1]*(float)b[1];
}
#endif

// One workgroup = one direction x two batch chains, persistent over all T steps.
// Thread t owns gate row g=t. Whh row lives in 64 VGPRs as packed f16 pairs.
// All global I/O is float32 (reference dtype).
__global__ __launch_bounds__(512) void bilstm_kernel(
    const float* __restrict__ x,
    const float* __restrict__ Wih_f, const float* __restrict__ Whh_f,
    const float* __restrict__ bih_f, const float* __restrict__ bhh_f,
    const float* __restrict__ Wih_b, const float* __restrict__ Whh_b,
    const float* __restrict__ bih_b, const float* __restrict__ bhh_b,
    float* __restrict__ out)
{
  __shared__ float xs[2][TLEN*IDIM];        // 16 KB: x for both batches (f32)
  __shared__ float gates[2][GDIM];          //  4 KB: activated gate values
  __shared__ __align__(8) u16 hs[2*HDIM];   // packed f16 h: idx = (j>>1)*4 + b*2 + (j&1)

  const int tid = threadIdx.x;
  const int wg  = blockIdx.x;
  const int dir = wg >> 7;                  // 0 = fwd, 1 = bwd
  const int b0  = (wg & 127) * 2;

  const float* Wih = dir ? Wih_b : Wih_f;
  const float* Whh = dir ? Whh_b : Whh_f;
  const float* bih = dir ? bih_b : bih_f;
  const float* bhh = dir ? bhh_b : bhh_f;

  const int g = tid;                        // gate row 0..511 (i,f,g,o blocks of 128)

  // input-projection row (4 f32) + combined bias
  const float4 wiv = *(const float4*)(Wih + g*IDIM);
  const float bias = bih[g] + bhh[g];

  // Whh row (128 f32) -> 64 packed f16 pairs in registers
  u32 wpk[64];
  {
    const float4* wr = (const float4*)(Whh + g*HDIM);
    #pragma unroll
    for (int i = 0; i < 32; ++i){
      float4 q = wr[i];
      half2v h0 = { (_Float16)q.x, (_Float16)q.y };
      half2v h1 = { (_Float16)q.z, (_Float16)q.w };
      wpk[i*2+0] = __builtin_bit_cast(u32, h0);
      wpk[i*2+1] = __builtin_bit_cast(u32, h1);
    }
  }

  // stage x for both batches (coalesced float4 loads: 2048 floats each)
  {
    const float4* src0 = (const float4*)(x + (size_t)(b0+0)*TLEN*IDIM);
    const float4* src1 = (const float4*)(x + (size_t)(b0+1)*TLEN*IDIM);
    ((float4*)xs[0])[tid] = src0[tid];
    ((float4*)xs[1])[tid] = src1[tid];
  }
  if (tid < 2*HDIM) hs[tid] = 0;

  float c = 0.0f, hout = 0.0f;              // valid on threads < 256
  __syncthreads();

  for (int s = 0; s < TLEN; ++s){
    const int tt = dir ? (TLEN-1-s) : s;

    // input projection (broadcast LDS reads, f32 fma)
    const float4 xv0 = ((const float4*)xs[0])[tt];
    const float4 xv1 = ((const float4*)xs[1])[tt];
    float acc0 = bias + wiv.x*xv0.x + wiv.y*xv0.y + wiv.z*xv0.z + wiv.w*xv0.w;
    float acc1 = bias + wiv.x*xv1.x + wiv.y*xv1.y + wiv.z*xv1.z + wiv.w*xv1.w;

    // recurrent GEMV: 64 broadcast b64 reads + 128 v_dot2_f32_f16
    const uint2* hp = (const uint2*)hs;
    #pragma unroll
    for (int k2 = 0; k2 < 64; ++k2){
      uint2 hv = hp[k2];
      half2v w = __builtin_bit_cast(half2v, wpk[k2]);
      acc0 = fdot2(w, __builtin_bit_cast(half2v, hv.x), acc0);
      acc1 = fdot2(w, __builtin_bit_cast(half2v, hv.y), acc1);
    }

    // activation (wave-uniform branch: 2 waves per gate type)
    float v0, v1;
    if ((g >> 7) == 2){ v0 = tanh_fast(acc0); v1 = tanh_fast(acc1); }
    else              { v0 = sigm(acc0);      v1 = sigm(acc1); }
    gates[0][g] = v0;
    gates[1][g] = v1;
    __syncthreads();

    // c/h update: thread t<256 owns (b, j); c stays in register (f32)
    if (tid < 2*HDIM){
      const int b = tid >> 7, j = tid & (HDIM-1);
      float iv = gates[b][j];
      float fv = gates[b][j+128];
      float gv = gates[b][j+256];
      float ov = gates[b][j+384];
      c = fv*c + iv*gv;
      hout = ov * tanh_fast(c);
      _Float16 hh = (_Float16)hout;
      hs[(j>>1)*4 + b*2 + (j&1)] = __builtin_bit_cast(u16, hh);
    }
    __syncthreads();
  }

  // final h_T -> out[b, dir*128 + j], f32
  if (tid < 2*HDIM){
    const int b = tid >> 7, j = tid & (HDIM-1);
    out[(size_t)(b0+b)*(2*HDIM) + dir*HDIM + j] = hout;
  }
}

extern "C" void kernel_launch(void* const* d_in, const int* in_sizes, int n_in,
                              void* d_out, int out_size, void* d_ws, size_t ws_size,
                              hipStream_t stream)
{
  const float* x     = (const float*)d_in[0];
  const float* Wih_f = (const float*)d_in[1];
  const float* Whh_f = (const float*)d_in[2];
  const float* bih_f = (const float*)d_in[3];
  const float* bhh_f = (const float*)d_in[4];
  const float* Wih_b = (const float*)d_in[5];
  const float* Whh_b = (const float*)d_in[6];
  const float* bih_b = (const float*)d_in[7];
  const float* bhh_b = (const float*)d_in[8];

  bilstm_kernel<<<dim3(256), dim3(512), 0, stream>>>(
      x, Wih_f, Whh_f, bih_f, bhh_f, Wih_b, Whh_b, bih_b, bhh_b,
      (float*)d_out);
}